// Round 1
// baseline (910.202 us; speedup 1.0000x reference)
//
#include <hip/hip_runtime.h>
#include <hip/hip_bf16.h>
#include <math.h>

// Problem constants (B=16384 rows, C=8192 classes), M=2.0, N=0.2, EPS=1e-5
#define BROWS 16384
#define CCOLS 8192
#define MARGIN_DIV 2.00001f
#define MARGIN_SHIFT 0.2f

// ---------------- setup kernels (tiny) ----------------

__global__ void k0_init(int* __restrict__ first_occ, int* __restrict__ cnt,
                        int* __restrict__ ctr) {
    int idx = blockIdx.x * 256 + threadIdx.x;
    if (idx < CCOLS) {
        first_occ[idx] = 0x7fffffff;
        cnt[idx] = 0;
        ctr[idx] = 0;
    }
}

__global__ void k1_hist(const int* __restrict__ labels, int* __restrict__ first_occ,
                        int* __restrict__ cnt) {
    int r = blockIdx.x * 256 + threadIdx.x;
    if (r < BROWS) {
        int lab = labels[r];
        atomicMin(&first_occ[lab], r);
        atomicAdd(&cnt[lab], 1);
    }
}

// grpcnt[p] = cnt[label[p]] if p is the first occurrence of its label else 0
__global__ void k2_grpcnt(const int* __restrict__ labels, const int* __restrict__ first_occ,
                          const int* __restrict__ cnt, int* __restrict__ grpcnt) {
    int p = blockIdx.x * 256 + threadIdx.x;
    if (p < BROWS) {
        int lab = labels[p];
        grpcnt[p] = (first_occ[lab] == p) ? cnt[lab] : 0;
    }
}

// exclusive scan of grpcnt (BROWS elements), single block, 256 threads x 64 elems
__global__ void k3_scan(const int* __restrict__ grpcnt, int* __restrict__ scanarr) {
    __shared__ int sums[256];
    int t = threadIdx.x;
    int base = t * 64;
    int local = 0;
    for (int j = 0; j < 64; j++) local += grpcnt[base + j];
    sums[t] = local;
    __syncthreads();
    for (int off = 1; off < 256; off <<= 1) {
        int v = (t >= off) ? sums[t - off] : 0;
        __syncthreads();
        sums[t] += v;
        __syncthreads();
    }
    int run = sums[t] - local;  // exclusive prefix for this chunk
    for (int j = 0; j < 64; j++) {
        scanarr[base + j] = run;
        run += grpcnt[base + j];
    }
}

// scatter each row into its label's bucket (unordered slots)
__global__ void k4_bucket(const int* __restrict__ labels, const int* __restrict__ first_occ,
                          const int* __restrict__ scanarr, int* __restrict__ ctr,
                          int* __restrict__ bucket) {
    int r = blockIdx.x * 256 + threadIdx.x;
    if (r < BROWS) {
        int lab = labels[r];
        int slot = atomicAdd(&ctr[lab], 1);
        int base = scanarr[first_occ[lab]];
        bucket[base + slot] = r;
    }
}

// sort each tiny bucket ascending (restores stability) -> bucket becomes perm
__global__ void k5_sortgroups(const int* __restrict__ first_occ, const int* __restrict__ cnt,
                              const int* __restrict__ scanarr, int* __restrict__ bucket) {
    int c = blockIdx.x * 256 + threadIdx.x;
    if (c < CCOLS) {
        int n = cnt[c];
        if (n > 1) {
            int base = scanarr[first_occ[c]];
            for (int a = 1; a < n; a++) {
                int key = bucket[base + a];
                int b = a - 1;
                while (b >= 0 && bucket[base + b] > key) {
                    bucket[base + b + 1] = bucket[base + b];
                    b--;
                }
                bucket[base + b + 1] = key;
            }
        }
    }
}

// ---------------- main fused kernel ----------------
// block i: read input row perm[i], apply margin at label col, write output row i,
// compute logsumexp and partial loss.
__global__ __launch_bounds__(256) void k6_main(const float* __restrict__ logits,
                                               const int* __restrict__ labels,
                                               const int* __restrict__ perm,
                                               float* __restrict__ out,
                                               float* __restrict__ partials) {
    int i = blockIdx.x;          // output row
    int r = perm[i];             // input row
    int lab = labels[r];
    const float4* src = (const float4*)(logits + (size_t)r * CCOLS);
    float4* dst = (float4*)(out + (size_t)i * CCOLS);
    int t = threadIdx.x;

    float4 v[8];
    float tmax = -INFINITY;
    float tval = 0.0f;
    bool havet = false;

    #pragma unroll
    for (int k = 0; k < 8; k++) {
        int f4 = t + k * 256;
        float4 x = src[f4];
        int col = f4 * 4;
        if (col <= lab && lab < col + 4) {
            float* xp = (float*)&x;
            float vv = xp[lab - col];
            vv = (vv > 0.0f) ? (vv / MARGIN_DIV - MARGIN_SHIFT)
                             : (vv * MARGIN_DIV - MARGIN_SHIFT);
            xp[lab - col] = vv;
            tval = vv;
            havet = true;
        }
        v[k] = x;
        tmax = fmaxf(tmax, fmaxf(fmaxf(x.x, x.y), fmaxf(x.z, x.w)));
    }

    __shared__ float smax[4], ssum[4], stval;
    int wave = t >> 6, lane = t & 63;
    #pragma unroll
    for (int off = 32; off > 0; off >>= 1)
        tmax = fmaxf(tmax, __shfl_down(tmax, off, 64));
    if (lane == 0) smax[wave] = tmax;
    if (havet) stval = tval;
    __syncthreads();
    float rmax = fmaxf(fmaxf(smax[0], smax[1]), fmaxf(smax[2], smax[3]));

    float tsum = 0.0f;
    #pragma unroll
    for (int k = 0; k < 8; k++) {
        float4 x = v[k];
        tsum += __expf(x.x - rmax) + __expf(x.y - rmax) +
                __expf(x.z - rmax) + __expf(x.w - rmax);
        dst[t + k * 256] = x;
    }
    #pragma unroll
    for (int off = 32; off > 0; off >>= 1)
        tsum += __shfl_down(tsum, off, 64);
    if (lane == 0) ssum[wave] = tsum;
    __syncthreads();

    if (t == 0) {
        float s = ssum[0] + ssum[1] + ssum[2] + ssum[3];
        partials[i] = (rmax + __logf(s)) - stval;         // lse - target
        out[(size_t)BROWS * CCOLS + i] = (float)lab;      // permuted label output
    }
}

// final loss: mean(partials)
__global__ void k7_loss(const float* __restrict__ partials, float* __restrict__ out_loss) {
    __shared__ float s[256];
    int t = threadIdx.x;
    float a = 0.0f;
    for (int j = t; j < BROWS; j += 256) a += partials[j];
    s[t] = a;
    __syncthreads();
    for (int off = 128; off > 0; off >>= 1) {
        if (t < off) s[t] += s[t + off];
        __syncthreads();
    }
    if (t == 0) *out_loss = s[0] / (float)BROWS;
}

extern "C" void kernel_launch(void* const* d_in, const int* in_sizes, int n_in,
                              void* d_out, int out_size, void* d_ws, size_t ws_size,
                              hipStream_t stream) {
    const float* logits = (const float*)d_in[0];
    const int* labels = (const int*)d_in[1];
    float* out = (float*)d_out;

    // workspace layout
    int* first_occ = (int*)d_ws;             // C
    int* cnt = first_occ + CCOLS;            // C
    int* ctr = cnt + CCOLS;                  // C
    int* grpcnt = ctr + CCOLS;               // B
    int* scanarr = grpcnt + BROWS;           // B
    int* perm = scanarr + BROWS;             // B (bucket -> perm after sort)
    float* partials = (float*)(perm + BROWS); // B

    k0_init<<<CCOLS / 256, 256, 0, stream>>>(first_occ, cnt, ctr);
    k1_hist<<<BROWS / 256, 256, 0, stream>>>(labels, first_occ, cnt);
    k2_grpcnt<<<BROWS / 256, 256, 0, stream>>>(labels, first_occ, cnt, grpcnt);
    k3_scan<<<1, 256, 0, stream>>>(grpcnt, scanarr);
    k4_bucket<<<BROWS / 256, 256, 0, stream>>>(labels, first_occ, scanarr, ctr, perm);
    k5_sortgroups<<<CCOLS / 256, 256, 0, stream>>>(first_occ, cnt, scanarr, perm);
    k6_main<<<BROWS, 256, 0, stream>>>(logits, labels, perm, out, partials);
    k7_loss<<<1, 256, 0, stream>>>(partials, out + (size_t)BROWS * CCOLS + BROWS);
}